// Round 2
// baseline (916.207 us; speedup 1.0000x reference)
//
#include <hip/hip_runtime.h>
#include <hip/hip_bf16.h>
#include <stdint.h>

// Problem constants (reference: OUT=4096, IN=4096, x = [8,2048,4096] fp32)
#define K_DIM 4096
#define N_DIM 4096
#define M_DIM 16384

// 256^2 8-phase template (m201-class): BM=BN=256, BK=64, 8 waves (2Mx4N)
#define BM 256
#define BN 256
#define BK 64
#define NT (K_DIM / BK)   // 64 K-tiles

typedef short short8 __attribute__((ext_vector_type(8)));      // 8 bf16 MFMA A/B frag
typedef float floatx4 __attribute__((ext_vector_type(4)));     // MFMA C/D frag
typedef unsigned short ushort4v __attribute__((ext_vector_type(4)));
typedef unsigned short ushort8 __attribute__((ext_vector_type(8)));

typedef __attribute__((address_space(3))) unsigned int lds_u32;
typedef const __attribute__((address_space(1))) unsigned int glb_u32;

__constant__ float NF4_LUT[16] = {
    -1.0f, -0.6961928009986877f, -0.5250730514526367f, -0.39491748809814453f,
    -0.28444138169288635f, -0.18477343022823334f, -0.09105003625154495f, 0.0f,
    0.07958029955625534f, 0.16093020141124725f, 0.24611230194568634f,
    0.33791524171829224f, 0.44070982933044434f, 0.5626170039176941f,
    0.7229568362236023f, 1.0f};

__device__ __forceinline__ unsigned short f2bf(float f) {
    union { float f; unsigned int u; } v; v.f = f;
    return (unsigned short)((v.u + 0x7FFFu + ((v.u >> 16) & 1u)) >> 16);  // RNE
}

// ---- Phase 1: x fp32 -> bf16 ----
__global__ __launch_bounds__(256) void cvt_x_kernel(const float4* __restrict__ x4,
                                                    ushort4v* __restrict__ xb4) {
    int g = blockIdx.x * 256 + threadIdx.x;       // 8 floats per thread
    int i0 = ((g >> 6) << 7) + (g & 63);          // wave-contiguous float4 index
    int i1 = i0 + 64;
    float4 a = x4[i0];
    float4 b = x4[i1];
    ushort4v oa, ob;
    oa[0] = f2bf(a.x); oa[1] = f2bf(a.y); oa[2] = f2bf(a.z); oa[3] = f2bf(a.w);
    ob[0] = f2bf(b.x); ob[1] = f2bf(b.y); ob[2] = f2bf(b.z); ob[3] = f2bf(b.w);
    xb4[i0] = oa;
    xb4[i1] = ob;
}

// ---- Phase 2: NF4 unpack -> bf16 W [N][K] ----
// LDS lut: 16 floats live in banks 0..15, one value per bank -> every access
// to a bank is the same address -> broadcast, zero conflicts.
__global__ __launch_bounds__(256) void dequant_w_kernel(const int4* __restrict__ wp4,
                                                        const float* __restrict__ scale,
                                                        ushort8* __restrict__ wb) {
    __shared__ float lut[16];
    if (threadIdx.x < 16) lut[threadIdx.x] = NF4_LUT[threadIdx.x] * scale[0];
    __syncthreads();
    int i = blockIdx.x * 256 + threadIdx.x;   // 4 packed ints -> 8 bf16 per thread
    int4 p = wp4[i];
    ushort8 o;
    o[0] = f2bf(lut[p.x & 15]); o[1] = f2bf(lut[(p.x >> 4) & 15]);
    o[2] = f2bf(lut[p.y & 15]); o[3] = f2bf(lut[(p.y >> 4) & 15]);
    o[4] = f2bf(lut[p.z & 15]); o[5] = f2bf(lut[(p.z >> 4) & 15]);
    o[6] = f2bf(lut[p.w & 15]); o[7] = f2bf(lut[(p.w >> 4) & 15]);
    wb[i] = o;
}

// ---- Phase 3: C[M][N] = A[M][K] * B[N][K]^T + bias ----
// 256^2 tile, BK=64, 8 waves. 8-phase counted-vmcnt schedule (T1+T2+T3+T4+T5):
// per K-tile 4 phases, each {ds_read quadrant || stage 1 half-tile -> s_barrier
// -> lgkmcnt(0) -> setprio(1) 16xMFMA setprio(0) -> s_barrier}. vmcnt(4) once
// per K-tile (ph4) -- never drained to 0 in the main loop.
//
// LDS swizzle (rule #21: linear dest + inverse-swz SOURCE + swz on READ):
// row-major [256 rows][8 slots of 16B]; LDS[row][slot] holds global chunk
// (slot ^ (row&7)). global_load_lds keeps its required linear dest
// (wave-uniform base + lane*16); the XOR is applied to the per-lane GLOBAL
// source column. Frag reads use slot = (ksub*4+quad) ^ (r15&7): chunk-column
// = quad^(r15&7) -> exactly 8 lanes per 16B column x 8 columns = all 32 banks
// busy every cycle = wave64 ds_read_b128 conflict-free floor.
//
// Race-freedom (barrier-enforced, no timing assumptions):
//   A(t+1) -> buffer (t+1)&1 at ph1/ph2: region last read tile t-1 (barriers
//     in between; reads completed at that tile's lgkmcnt(0)).
//   B(t+2) -> buffer t&1 at ph3/ph4: region's only reader is tile-top bq
//     ds_read, complete by ph1's lgkmcnt(0), two barriers before ph3 issue.
//   vmcnt(4) at ph4 retires everything up to A(t+1) (newest 4 = B(t+2)) =>
//   tile t+1 fully landed before its reads; B(t+2) stays in flight.

__device__ __forceinline__ void mfma_quad(floatx4 (&acc0)[4], floatx4 (&acc1)[4],
                                          const short8 (&bq)[4][2],
                                          short8 a00, short8 a01, short8 a10, short8 a11) {
#pragma unroll
    for (int ni = 0; ni < 4; ++ni)
        acc0[ni] = __builtin_amdgcn_mfma_f32_16x16x32_bf16(a00, bq[ni][0], acc0[ni], 0, 0, 0);
#pragma unroll
    for (int ni = 0; ni < 4; ++ni)
        acc1[ni] = __builtin_amdgcn_mfma_f32_16x16x32_bf16(a10, bq[ni][0], acc1[ni], 0, 0, 0);
#pragma unroll
    for (int ni = 0; ni < 4; ++ni)
        acc0[ni] = __builtin_amdgcn_mfma_f32_16x16x32_bf16(a01, bq[ni][1], acc0[ni], 0, 0, 0);
#pragma unroll
    for (int ni = 0; ni < 4; ++ni)
        acc1[ni] = __builtin_amdgcn_mfma_f32_16x16x32_bf16(a11, bq[ni][1], acc1[ni], 0, 0, 0);
}

__global__ __launch_bounds__(512) void gemm_bt_kernel(const unsigned short* __restrict__ A,
                                                      const unsigned short* __restrict__ Bw,
                                                      const float* __restrict__ bias,
                                                      float* __restrict__ C) {
    // [buf][op][256 rows * 64 cols] bf16 = 128 KiB (1 block/CU)
    __shared__ __align__(16) unsigned short ls[2][2][BM * BK];

    const int t    = threadIdx.x;
    const int wave = t >> 6;
    const int lane = t & 63;
    const int r15  = lane & 15;
    const int quad = lane >> 4;
    const int wm   = wave >> 2;        // 0..1 (M split)
    const int wn   = wave & 3;         // 0..3 (N split)

    // Bijective XCD swizzle: 1024 wgs, 1024 % 8 == 0. Each XCD gets 128
    // consecutive wgs = 8 M-panels x 16 N-blocks -> A-panel reuse in its L2.
    const int bid = blockIdx.x;
    const int wg  = (bid & 7) * 128 + (bid >> 3);
    const int bm0 = (wg >> 4) * BM;    // 64 M-blocks
    const int bn0 = (wg & 15) * BN;    // 16 N-blocks

    // ---- staging addresses (chunk = t; row = t>>3, slot = t&7, linear dest)
    const int rl = t >> 3;                          // rows 0..63 per load
    const int gc = ((t & 7) ^ (rl & 7)) << 3;       // inverse-swizzled global col
    const unsigned short* gA0 = A  + (size_t)(bm0 + rl) * K_DIM + gc;
    const unsigned short* gB0 = Bw + (size_t)(bn0 + rl) * K_DIM + gc;

    unsigned short* lsf = &ls[0][0][0];
    const int stA = wave * 512;                     // wave-uniform lds ushort base

    // ---- frag-read offsets (ushorts) ----
    const int x    = r15 & 7;
    const int sl0  = (quad ^ x) << 3;               // ksub=0 slot (chunks 0..3)
    const int sl1  = ((quad + 4) ^ x) << 3;         // ksub=1 slot (chunks 4..7)
    const int aRow = (wm * 128 + r15) * BK;
    const int bRow = BM * BK + (wn * 64 + r15) * BK;   // +16384 = B operand base

    floatx4 acc[8][4];
#pragma unroll
    for (int i = 0; i < 8; ++i)
#pragma unroll
        for (int j = 0; j < 4; ++j)
            acc[i][j] = (floatx4){0.f, 0.f, 0.f, 0.f};

#define STG(GBASE, OP, H, KT, BUF)                                                          \
    do {                                                                                    \
        const unsigned short* _g = (GBASE) + (size_t)(H) * 128 * K_DIM + (size_t)(KT) * BK; \
        unsigned short* _l = lsf + ((BUF) * 2 + (OP)) * (BM * BK) + (H) * 8192 + stA;       \
        __builtin_amdgcn_global_load_lds((glb_u32*)_g, (lds_u32*)_l, 16, 0, 0);             \
        __builtin_amdgcn_global_load_lds((glb_u32*)(_g + (size_t)64 * K_DIM),               \
                                         (lds_u32*)(_l + 4096), 16, 0, 0);                  \
    } while (0)

#define LDA(LB, MI, SL) (*(const short8*)((LB) + aRow + (MI)*1024 + (SL)))
#define LDB(LB, NI, SL) (*(const short8*)((LB) + bRow + (NI)*1024 + (SL)))

#define NOWAIT ((void)0)

#define PHASE(LB, Q, STAGE_CODE, WAIT_CODE)                                \
    {                                                                      \
        short8 a00 = LDA(LB, 2 * (Q),     sl0);                            \
        short8 a01 = LDA(LB, 2 * (Q),     sl1);                            \
        short8 a10 = LDA(LB, 2 * (Q) + 1, sl0);                            \
        short8 a11 = LDA(LB, 2 * (Q) + 1, sl1);                            \
        STAGE_CODE;                                                        \
        __builtin_amdgcn_s_barrier();                                      \
        asm volatile("s_waitcnt lgkmcnt(0)" ::: "memory");                 \
        __builtin_amdgcn_s_setprio(1);                                     \
        mfma_quad(acc[2 * (Q)], acc[2 * (Q) + 1], bq, a00, a01, a10, a11); \
        __builtin_amdgcn_s_setprio(0);                                     \
        WAIT_CODE;                                                         \
        __builtin_amdgcn_s_barrier();                                      \
    }

#define TILE(T, BUF)                                                                   \
    {                                                                                  \
        const unsigned short* lb = lsf + (BUF) * (2 * BM * BK);                        \
        _Pragma("unroll") for (int ni = 0; ni < 4; ++ni) {                             \
            bq[ni][0] = LDB(lb, ni, sl0);                                              \
            bq[ni][1] = LDB(lb, ni, sl1);                                              \
        }                                                                              \
        PHASE(lb, 0, if ((T) + 1 < NT) STG(gA0, 0, 0, (T) + 1, 1 - (BUF)), NOWAIT);    \
        PHASE(lb, 1, if ((T) + 1 < NT) STG(gA0, 0, 1, (T) + 1, 1 - (BUF)), NOWAIT);    \
        PHASE(lb, 2, if ((T) + 2 < NT) STG(gB0, 1, 0, (T) + 2, (BUF)), NOWAIT);        \
        PHASE(lb, 3, if ((T) + 2 < NT) STG(gB0, 1, 1, (T) + 2, (BUF)),                 \
              if ((T) + 2 < NT) { asm volatile("s_waitcnt vmcnt(4)" ::: "memory"); }   \
              else { asm volatile("s_waitcnt vmcnt(0)" ::: "memory"); });              \
    }

    // ---- prologue: tile0 {A0,A1,B0,B1} -> buf0; tile1 {B0,B1} -> buf1 ----
    STG(gA0, 0, 0, 0, 0);
    STG(gA0, 0, 1, 0, 0);
    STG(gB0, 1, 0, 0, 0);
    STG(gB0, 1, 1, 0, 0);
    STG(gB0, 1, 0, 1, 1);
    STG(gB0, 1, 1, 1, 1);
    asm volatile("s_waitcnt vmcnt(4)" ::: "memory");   // tile0 landed; tile1.B in flight
    __builtin_amdgcn_s_barrier();

    short8 bq[4][2];
    for (int kt = 0; kt < NT; kt += 2) {
        TILE(kt, 0);
        TILE(kt + 1, 1);
    }

    // ---- epilogue: D col(n)=lane&15, row(m)=quad*4+reg [m89-verified] ----
#pragma unroll
    for (int ni = 0; ni < 4; ++ni) {
        const int n = bn0 + wn * 64 + ni * 16 + r15;
        const float bv = bias[n];
#pragma unroll
        for (int mi = 0; mi < 8; ++mi) {
            const int m0 = bm0 + wm * 128 + mi * 16 + quad * 4;
            float* cp = C + (size_t)m0 * N_DIM + n;
#pragma unroll
            for (int r = 0; r < 4; ++r)
                cp[(size_t)r * N_DIM] = acc[mi][ni][r] + bv;
        }
    }
#undef STG
#undef LDA
#undef LDB
#undef NOWAIT
#undef PHASE
#undef TILE
}

extern "C" void kernel_launch(void* const* d_in, const int* in_sizes, int n_in,
                              void* d_out, int out_size, void* d_ws, size_t ws_size,
                              hipStream_t stream) {
    const float* x     = (const float*)d_in[0];
    const int*   wp    = (const int*)d_in[1];
    const float* scale = (const float*)d_in[2];
    const float* bias  = (const float*)d_in[3];
    float*       out   = (float*)d_out;

    // ws layout: [0, 128 MiB) x_bf16 ; [128 MiB, 160 MiB) W_bf16
    unsigned short* xb = (unsigned short*)d_ws;
    unsigned short* wb = (unsigned short*)((char*)d_ws + (size_t)M_DIM * K_DIM * 2);

    cvt_x_kernel<<<(M_DIM * (size_t)K_DIM) / 8 / 256, 256, 0, stream>>>(
        (const float4*)x, (ushort4v*)xb);
    dequant_w_kernel<<<(N_DIM * (size_t)K_DIM / 2) / 4 / 256, 256, 0, stream>>>(
        (const int4*)wp, scale, (ushort8*)wb);

    dim3 grid((M_DIM / BM) * (N_DIM / BN));  // 64*16 = 1024, XCD-swizzled in-kernel
    gemm_bt_kernel<<<grid, 512, 0, stream>>>(xb, wb, bias, out);
}

// Round 3
// 902.278 us; speedup vs baseline: 1.0154x; 1.0154x over previous
//
#include <hip/hip_runtime.h>
#include <hip/hip_bf16.h>
#include <stdint.h>

// Problem constants (reference: OUT=4096, IN=4096, x = [8,2048,4096] fp32)
#define K_DIM 4096
#define N_DIM 4096
#define M_DIM 16384

// 256^2 8-phase template (m201-class): BM=BN=256, BK=64, 8 waves (2Mx4N)
#define BM 256
#define BN 256
#define BK 64
#define NT (K_DIM / BK)   // 64 K-tiles

typedef short short8 __attribute__((ext_vector_type(8)));      // 8 bf16 MFMA A/B frag
typedef float floatx4 __attribute__((ext_vector_type(4)));     // MFMA C/D frag
typedef unsigned short ushort4v __attribute__((ext_vector_type(4)));
typedef unsigned short ushort8 __attribute__((ext_vector_type(8)));

typedef __attribute__((address_space(3))) unsigned int lds_u32;
typedef const __attribute__((address_space(1))) unsigned int glb_u32;

__constant__ float NF4_LUT[16] = {
    -1.0f, -0.6961928009986877f, -0.5250730514526367f, -0.39491748809814453f,
    -0.28444138169288635f, -0.18477343022823334f, -0.09105003625154495f, 0.0f,
    0.07958029955625534f, 0.16093020141124725f, 0.24611230194568634f,
    0.33791524171829224f, 0.44070982933044434f, 0.5626170039176941f,
    0.7229568362236023f, 1.0f};

__device__ __forceinline__ unsigned short f2bf(float f) {
    union { float f; unsigned int u; } v; v.f = f;
    return (unsigned short)((v.u + 0x7FFFu + ((v.u >> 16) & 1u)) >> 16);  // RNE
}

// ---- Phase 1: x fp32 -> bf16 ----
__global__ __launch_bounds__(256) void cvt_x_kernel(const float4* __restrict__ x4,
                                                    ushort4v* __restrict__ xb4) {
    int g = blockIdx.x * 256 + threadIdx.x;       // 8 floats per thread
    int i0 = ((g >> 6) << 7) + (g & 63);          // wave-contiguous float4 index
    int i1 = i0 + 64;
    float4 a = x4[i0];
    float4 b = x4[i1];
    ushort4v oa, ob;
    oa[0] = f2bf(a.x); oa[1] = f2bf(a.y); oa[2] = f2bf(a.z); oa[3] = f2bf(a.w);
    ob[0] = f2bf(b.x); ob[1] = f2bf(b.y); ob[2] = f2bf(b.z); ob[3] = f2bf(b.w);
    xb4[i0] = oa;
    xb4[i1] = ob;
}

// ---- Phase 2: NF4 unpack -> bf16 W [N][K] ----
__global__ __launch_bounds__(256) void dequant_w_kernel(const int4* __restrict__ wp4,
                                                        const float* __restrict__ scale,
                                                        ushort8* __restrict__ wb) {
    __shared__ float lut[16];
    if (threadIdx.x < 16) lut[threadIdx.x] = NF4_LUT[threadIdx.x] * scale[0];
    __syncthreads();
    int i = blockIdx.x * 256 + threadIdx.x;   // 4 packed ints -> 8 bf16 per thread
    int4 p = wp4[i];
    ushort8 o;
    o[0] = f2bf(lut[p.x & 15]); o[1] = f2bf(lut[(p.x >> 4) & 15]);
    o[2] = f2bf(lut[p.y & 15]); o[3] = f2bf(lut[(p.y >> 4) & 15]);
    o[4] = f2bf(lut[p.z & 15]); o[5] = f2bf(lut[(p.z >> 4) & 15]);
    o[6] = f2bf(lut[p.w & 15]); o[7] = f2bf(lut[(p.w >> 4) & 15]);
    wb[i] = o;
}

// ---- Phase 3: C[M][N] = A[M][K] * B[N][K]^T + bias ----
// 256^2 tile, BK=64, 8 waves, 8-phase counted-vmcnt schedule.
// R2 measured: 517us, MfmaUtil 47.5, bank-conflict 0, no spill.
// R3 change (the only one): REMOVED the per-phase asm lgkmcnt(0). All ds_reads
// are IR loads -> compiler emits fine-grained per-use lgkmcnt (m97-verified),
// so MFMA starts as soon as its own operands land and the remaining reads
// (esp. ph1's 12-read cluster) drain UNDER the MFMA cluster instead of
// serializing all 8 waves at ~380 cyc/CU of idle matrix pipe per phase.
// Race argument unchanged: all bq reads are first-used in ph1's MFMA (forced
// wait) >= 2 barriers before ph3's B(t+2) overwrite; A-frag reads complete in
// their own phase; per-wave vmcnt + following barrier still gate every read
// of freshly-staged LDS (vmcnt is per-wave -- the barrier after it is what
// makes other waves' stages visible).
//
// LDS swizzle (rule #21): LDS[row][slot] holds global chunk (slot^(row&7));
// linear gload_lds dest, XOR applied to per-lane GLOBAL source col; frag reads
// use slot=(ksub*4+quad)^(r15&7) -> 8 lanes per 16B column = conflict-free
// floor (PMC-verified 0 conflicts).
//
// Staging race-freedom (barrier-order only, no timing assumptions):
//   A(t+1) -> buf (t+1)&1 at ph1/ph2: region last read tile t-1.
//   B(t+2) -> buf t&1 at ph3/ph4: region's only reader is tile-top bq reads,
//     complete by ph1 MFMA, two barriers before ph3 issue.
//   vmcnt(4) at ph4 (after MFMA, before barrier2) retires A(t+1); barrier2
//   publishes all waves' stages -> tile t+1 reads are safe.

__device__ __forceinline__ void mfma_quad(floatx4 (&acc0)[4], floatx4 (&acc1)[4],
                                          const short8 (&bq)[4][2],
                                          short8 a00, short8 a01, short8 a10, short8 a11) {
#pragma unroll
    for (int ni = 0; ni < 4; ++ni)
        acc0[ni] = __builtin_amdgcn_mfma_f32_16x16x32_bf16(a00, bq[ni][0], acc0[ni], 0, 0, 0);
#pragma unroll
    for (int ni = 0; ni < 4; ++ni)
        acc1[ni] = __builtin_amdgcn_mfma_f32_16x16x32_bf16(a10, bq[ni][0], acc1[ni], 0, 0, 0);
#pragma unroll
    for (int ni = 0; ni < 4; ++ni)
        acc0[ni] = __builtin_amdgcn_mfma_f32_16x16x32_bf16(a01, bq[ni][1], acc0[ni], 0, 0, 0);
#pragma unroll
    for (int ni = 0; ni < 4; ++ni)
        acc1[ni] = __builtin_amdgcn_mfma_f32_16x16x32_bf16(a11, bq[ni][1], acc1[ni], 0, 0, 0);
}

__global__ __launch_bounds__(512) void gemm_bt_kernel(const unsigned short* __restrict__ A,
                                                      const unsigned short* __restrict__ Bw,
                                                      const float* __restrict__ bias,
                                                      float* __restrict__ C) {
    // [buf][op][256 rows * 64 cols] bf16 = 128 KiB (1 block/CU)
    __shared__ __align__(16) unsigned short ls[2][2][BM * BK];

    const int t    = threadIdx.x;
    const int wave = t >> 6;
    const int lane = t & 63;
    const int r15  = lane & 15;
    const int quad = lane >> 4;
    const int wm   = wave >> 2;        // 0..1 (M split)
    const int wn   = wave & 3;         // 0..3 (N split)

    // Bijective XCD swizzle: 1024 wgs % 8 == 0. Each XCD gets 128 consecutive
    // wgs = 8 M-panels x 16 N-blocks -> A-panel (2 MiB) reuse in its 4 MiB L2.
    const int bid = blockIdx.x;
    const int wg  = (bid & 7) * 128 + (bid >> 3);
    const int bm0 = (wg >> 4) * BM;    // 64 M-blocks
    const int bn0 = (wg & 15) * BN;    // 16 N-blocks

    // ---- staging addresses (chunk = t; row = t>>3, slot = t&7, linear dest)
    const int rl = t >> 3;                          // rows 0..63 per load
    const int gc = ((t & 7) ^ (rl & 7)) << 3;       // inverse-swizzled global col
    const unsigned short* gA0 = A  + (size_t)(bm0 + rl) * K_DIM + gc;
    const unsigned short* gB0 = Bw + (size_t)(bn0 + rl) * K_DIM + gc;

    unsigned short* lsf = &ls[0][0][0];
    const int stA = wave * 512;                     // wave-uniform lds ushort base

    // ---- frag-read offsets (ushorts) ----
    const int x    = r15 & 7;
    const int sl0  = (quad ^ x) << 3;               // ksub=0 slot (chunks 0..3)
    const int sl1  = ((quad + 4) ^ x) << 3;         // ksub=1 slot (chunks 4..7)
    const int aRow = (wm * 128 + r15) * BK;
    const int bRow = BM * BK + (wn * 64 + r15) * BK;   // +16384 = B operand base

    floatx4 acc[8][4];
#pragma unroll
    for (int i = 0; i < 8; ++i)
#pragma unroll
        for (int j = 0; j < 4; ++j)
            acc[i][j] = (floatx4){0.f, 0.f, 0.f, 0.f};

#define STG(GBASE, OP, H, KT, BUF)                                                          \
    do {                                                                                    \
        const unsigned short* _g = (GBASE) + (size_t)(H) * 128 * K_DIM + (size_t)(KT) * BK; \
        unsigned short* _l = lsf + ((BUF) * 2 + (OP)) * (BM * BK) + (H) * 8192 + stA;       \
        __builtin_amdgcn_global_load_lds((glb_u32*)_g, (lds_u32*)_l, 16, 0, 0);             \
        __builtin_amdgcn_global_load_lds((glb_u32*)(_g + (size_t)64 * K_DIM),               \
                                         (lds_u32*)(_l + 4096), 16, 0, 0);                  \
    } while (0)

#define LDA(LB, MI, SL) (*(const short8*)((LB) + aRow + (MI)*1024 + (SL)))
#define LDB(LB, NI, SL) (*(const short8*)((LB) + bRow + (NI)*1024 + (SL)))

#define NOWAIT ((void)0)

// R3: no asm lgkmcnt(0) after barrier -- compiler's fine-grained per-use
// lgkmcnt lets MFMA overlap the LDS drain.
#define PHASE(LB, Q, STAGE_CODE, WAIT_CODE)                                \
    {                                                                      \
        short8 a00 = LDA(LB, 2 * (Q),     sl0);                            \
        short8 a01 = LDA(LB, 2 * (Q),     sl1);                            \
        short8 a10 = LDA(LB, 2 * (Q) + 1, sl0);                            \
        short8 a11 = LDA(LB, 2 * (Q) + 1, sl1);                            \
        STAGE_CODE;                                                        \
        __builtin_amdgcn_s_barrier();                                      \
        __builtin_amdgcn_s_setprio(1);                                     \
        mfma_quad(acc[2 * (Q)], acc[2 * (Q) + 1], bq, a00, a01, a10, a11); \
        __builtin_amdgcn_s_setprio(0);                                     \
        WAIT_CODE;                                                         \
        __builtin_amdgcn_s_barrier();                                      \
    }

#define TILE(T, BUF)                                                                   \
    {                                                                                  \
        const unsigned short* lb = lsf + (BUF) * (2 * BM * BK);                        \
        _Pragma("unroll") for (int ni = 0; ni < 4; ++ni) {                             \
            bq[ni][0] = LDB(lb, ni, sl0);                                              \
            bq[ni][1] = LDB(lb, ni, sl1);                                              \
        }                                                                              \
        PHASE(lb, 0, if ((T) + 1 < NT) STG(gA0, 0, 0, (T) + 1, 1 - (BUF)), NOWAIT);    \
        PHASE(lb, 1, if ((T) + 1 < NT) STG(gA0, 0, 1, (T) + 1, 1 - (BUF)), NOWAIT);    \
        PHASE(lb, 2, if ((T) + 2 < NT) STG(gB0, 1, 0, (T) + 2, (BUF)), NOWAIT);        \
        PHASE(lb, 3, if ((T) + 2 < NT) STG(gB0, 1, 1, (T) + 2, (BUF)),                 \
              if ((T) + 2 < NT) { asm volatile("s_waitcnt vmcnt(4)" ::: "memory"); }   \
              else { asm volatile("s_waitcnt vmcnt(0)" ::: "memory"); });              \
    }

    // ---- prologue: tile0 {A0,A1,B0,B1} -> buf0; tile1 {B0,B1} -> buf1 ----
    STG(gA0, 0, 0, 0, 0);
    STG(gA0, 0, 1, 0, 0);
    STG(gB0, 1, 0, 0, 0);
    STG(gB0, 1, 1, 0, 0);
    STG(gB0, 1, 0, 1, 1);
    STG(gB0, 1, 1, 1, 1);
    asm volatile("s_waitcnt vmcnt(4)" ::: "memory");   // tile0 landed; tile1.B in flight
    __builtin_amdgcn_s_barrier();

    short8 bq[4][2];
    for (int kt = 0; kt < NT; kt += 2) {
        TILE(kt, 0);
        TILE(kt + 1, 1);
    }

    // ---- epilogue: D col(n)=lane&15, row(m)=quad*4+reg [m89-verified] ----
#pragma unroll
    for (int ni = 0; ni < 4; ++ni) {
        const int n = bn0 + wn * 64 + ni * 16 + r15;
        const float bv = bias[n];
#pragma unroll
        for (int mi = 0; mi < 8; ++mi) {
            const int m0 = bm0 + wm * 128 + mi * 16 + quad * 4;
            float* cp = C + (size_t)m0 * N_DIM + n;
#pragma unroll
            for (int r = 0; r < 4; ++r)
                cp[(size_t)r * N_DIM] = acc[mi][ni][r] + bv;
        }
    }
#undef STG
#undef LDA
#undef LDB
#undef NOWAIT
#undef PHASE
#undef TILE
}

extern "C" void kernel_launch(void* const* d_in, const int* in_sizes, int n_in,
                              void* d_out, int out_size, void* d_ws, size_t ws_size,
                              hipStream_t stream) {
    const float* x     = (const float*)d_in[0];
    const int*   wp    = (const int*)d_in[1];
    const float* scale = (const float*)d_in[2];
    const float* bias  = (const float*)d_in[3];
    float*       out   = (float*)d_out;

    // ws layout: [0, 128 MiB) x_bf16 ; [128 MiB, 160 MiB) W_bf16
    unsigned short* xb = (unsigned short*)d_ws;
    unsigned short* wb = (unsigned short*)((char*)d_ws + (size_t)M_DIM * K_DIM * 2);

    cvt_x_kernel<<<(M_DIM * (size_t)K_DIM) / 8 / 256, 256, 0, stream>>>(
        (const float4*)x, (ushort4v*)xb);
    dequant_w_kernel<<<(N_DIM * (size_t)K_DIM / 2) / 4 / 256, 256, 0, stream>>>(
        (const int4*)wp, scale, (ushort8*)wb);

    dim3 grid((M_DIM / BM) * (N_DIM / BN));  // 64*16 = 1024, XCD-swizzled in-kernel
    gemm_bt_kernel<<<grid, 512, 0, stream>>>(xb, wb, bias, out);
}